// Round 6
// baseline (166.790 us; speedup 1.0000x reference)
//
#include <hip/hip_runtime.h>
#include <hip/hip_bf16.h>
#include <math.h>

typedef __bf16 bf16x8 __attribute__((ext_vector_type(8)));
typedef float  f32x4  __attribute__((ext_vector_type(4)));
typedef unsigned short ushort_t;

#define LDK 72   // padded LDS row (bf16 elems): 144 B stride, conflict-free b128

// ws layout (bytes):
//   Kg  : [12][4096][64] bf16  (gathered, per-head)          @ 0        (6291456)
//   VgT : [12][64][4096] bf16  (gathered, transposed)        @ 6291456  (6291456)
//   l_acc: [4096*12] f32                                     @ 12582912 (196608)
#define KG_OFF  0
#define VGT_OFF 6291456
#define LACC_OFF 12582912

__device__ __forceinline__ int gather_pos(int gi, int group) {
    const int lsl = 10 + group;           // log2(segment length)
    const int seg = gi >> lsl;
    const int j   = gi - (seg << lsl);
    return (seg << lsl) + group + ((j & 1023) << group);
}

// ---------------- pre-convert: fp32 -> bf16, gather + transpose ----------------
__global__ __launch_bounds__(256)
void preconvert_kernel(const float* __restrict__ K, const float* __restrict__ V,
                       ushort_t* __restrict__ Kg, ushort_t* __restrict__ VgT)
{
    const int HD = 768;
    int b = blockIdx.x;
    const int tid = threadIdx.x;
    if (b < 768) {
        const int h = b % 12, gi0 = (b / 12) * 64;
        const int group = h >> 2;
        const int gi = gi0 + (tid >> 2);
        const int d0 = (tid & 3) << 4;
        const int pos = gather_pos(gi, group);
        const float* kp = K + (size_t)pos * HD + h * 64 + d0;
        float4 x0 = ((const float4*)kp)[0], x1 = ((const float4*)kp)[1];
        float4 x2 = ((const float4*)kp)[2], x3 = ((const float4*)kp)[3];
        bf16x8 w0, w1;
        w0[0]=(__bf16)x0.x; w0[1]=(__bf16)x0.y; w0[2]=(__bf16)x0.z; w0[3]=(__bf16)x0.w;
        w0[4]=(__bf16)x1.x; w0[5]=(__bf16)x1.y; w0[6]=(__bf16)x1.z; w0[7]=(__bf16)x1.w;
        w1[0]=(__bf16)x2.x; w1[1]=(__bf16)x2.y; w1[2]=(__bf16)x2.z; w1[3]=(__bf16)x2.w;
        w1[4]=(__bf16)x3.x; w1[5]=(__bf16)x3.y; w1[6]=(__bf16)x3.z; w1[7]=(__bf16)x3.w;
        ushort_t* out = Kg + ((size_t)(h * 4096 + gi)) * 64 + d0;
        *(bf16x8*)out = w0;
        *(bf16x8*)(out + 8) = w1;
    } else {
        b -= 768;
        const int h = b % 12, gi0 = (b / 12) * 64;
        const int group = h >> 2;
        __shared__ __align__(16) __bf16 Ts[64 * LDK];
        const int gil = tid >> 2;
        const int d0 = (tid & 3) << 4;
        const int pos = gather_pos(gi0 + gil, group);
        const float* vp = V + (size_t)pos * HD + h * 64 + d0;
        float4 x0 = ((const float4*)vp)[0], x1 = ((const float4*)vp)[1];
        float4 x2 = ((const float4*)vp)[2], x3 = ((const float4*)vp)[3];
        bf16x8 w0, w1;
        w0[0]=(__bf16)x0.x; w0[1]=(__bf16)x0.y; w0[2]=(__bf16)x0.z; w0[3]=(__bf16)x0.w;
        w0[4]=(__bf16)x1.x; w0[5]=(__bf16)x1.y; w0[6]=(__bf16)x1.z; w0[7]=(__bf16)x1.w;
        w1[0]=(__bf16)x2.x; w1[1]=(__bf16)x2.y; w1[2]=(__bf16)x2.z; w1[3]=(__bf16)x2.w;
        w1[4]=(__bf16)x3.x; w1[5]=(__bf16)x3.y; w1[6]=(__bf16)x3.z; w1[7]=(__bf16)x3.w;
        *(bf16x8*)&Ts[gil * LDK + d0]     = w0;
        *(bf16x8*)&Ts[gil * LDK + d0 + 8] = w1;
        __syncthreads();
        const int d = tid >> 2, c = tid & 3;
        bf16x8 o0, o1;
        #pragma unroll
        for (int i = 0; i < 8; ++i) {
            o0[i] = Ts[(c * 16 + i) * LDK + d];
            o1[i] = Ts[(c * 16 + 8 + i) * LDK + d];
        }
        ushort_t* out = VgT + ((size_t)(h * 64 + d)) * 4096 + gi0 + c * 16;
        *(bf16x8*)out = o0;
        *(bf16x8*)(out + 8) = o1;
    }
}

// -------- main attention: 128-row q-tiles, 32 q-rows/wave, split-K <=16 tiles --------
__global__ __launch_bounds__(256)
void dilated_attn_kernel(const float* __restrict__ Q,
                         const ushort_t* __restrict__ Kg,
                         const ushort_t* __restrict__ VgT,
                         const int* __restrict__ is_causal_p,
                         float* __restrict__ Out,
                         float* __restrict__ l_acc)
{
    const int HD = 768;
    // LPT: heaviest q-tiles first
    const int bx  = blockIdx.x;              // 0..1535
    const int qt  = 31 - (bx / 48);          // 128-row tile index
    const int rem = bx % 48;
    const int h   = rem % 12;
    const int c   = rem / 12;                // chunk 0..3
    const int group = h >> 2;
    const int sl    = 1024 << group;
    const int causal = (*is_causal_p) != 0;

    const int q0 = qt << 7;                  // 128-row tile base
    const int qb = q0 & (sl - 1);
    const int seg_start = q0 - qb;
    const int diag0 = qb >> 6;               // first diagonal k-tile
    const int nkt = causal ? (diag0 + 2) : (sl >> 6);
    const int kt0 = c << 4;
    if (kt0 >= nkt) return;
    const int kend = min(kt0 + 16, nkt);
    const int nch  = (nkt + 15) >> 4;

    const int tid  = threadIdx.x;
    const int wave = tid >> 6;
    const int lane = tid & 63;
    const int l15  = lane & 15;
    const int quad = lane >> 4;

    __shared__ __align__(16) __bf16 Ks[2][64 * LDK];   // [key][d]
    __shared__ __align__(16) __bf16 Vs[2][64 * LDK];   // [d][key]
    __shared__ __align__(16) __bf16 Ps[4][32 * LDK];   // per-wave P [row 0..31][key]

    const int srow = tid >> 3;
    const int scol = (tid & 7) << 3;
    const ushort_t* kg_head = Kg + (size_t)h * 4096 * 64;
    const ushort_t* vt_head = VgT + (size_t)h * 64 * 4096;

    // ---- Q fragments for 2 sub-strips (A-layout), scale = 0.125 * log2(e) ----
    bf16x8 a[2][2];
    {
        const float s = 0.125f * 1.4426950408889634f;
        #pragma unroll
        for (int sub = 0; sub < 2; ++sub) {
            const int qrow = q0 + wave * 32 + sub * 16 + l15;
            const float* qptr = Q + (size_t)qrow * HD + h * 64;
            float4 x0 = ((const float4*)(qptr + quad * 8))[0];
            float4 x1 = ((const float4*)(qptr + quad * 8))[1];
            float4 y0 = ((const float4*)(qptr + 32 + quad * 8))[0];
            float4 y1 = ((const float4*)(qptr + 32 + quad * 8))[1];
            a[sub][0][0]=(__bf16)(x0.x*s); a[sub][0][1]=(__bf16)(x0.y*s);
            a[sub][0][2]=(__bf16)(x0.z*s); a[sub][0][3]=(__bf16)(x0.w*s);
            a[sub][0][4]=(__bf16)(x1.x*s); a[sub][0][5]=(__bf16)(x1.y*s);
            a[sub][0][6]=(__bf16)(x1.z*s); a[sub][0][7]=(__bf16)(x1.w*s);
            a[sub][1][0]=(__bf16)(y0.x*s); a[sub][1][1]=(__bf16)(y0.y*s);
            a[sub][1][2]=(__bf16)(y0.z*s); a[sub][1][3]=(__bf16)(y0.w*s);
            a[sub][1][4]=(__bf16)(y1.x*s); a[sub][1][5]=(__bf16)(y1.y*s);
            a[sub][1][6]=(__bf16)(y1.z*s); a[sub][1][7]=(__bf16)(y1.w*s);
        }
    }

    f32x4 o[2][4];
    #pragma unroll
    for (int sub = 0; sub < 2; ++sub)
        #pragma unroll
        for (int t = 0; t < 4; ++t) o[sub][t] = (f32x4){0.f, 0.f, 0.f, 0.f};
    float l_r[8] = {0.f,0.f,0.f,0.f,0.f,0.f,0.f,0.f};

    bf16x8 kr0, kr1, vr0, vr1;
    auto load_tile = [&](int kt) {
        const ushort_t* kb = kg_head + (size_t)(seg_start + (kt << 6)) * 64;
        kr0 = *(const bf16x8*)(kb + srow * 64 + scol);
        kr1 = *(const bf16x8*)(kb + (srow + 32) * 64 + scol);
        const ushort_t* vb = vt_head + seg_start + (kt << 6);
        vr0 = *(const bf16x8*)(vb + (size_t)srow * 4096 + scol);
        vr1 = *(const bf16x8*)(vb + (size_t)(srow + 32) * 4096 + scol);
    };
    auto store_tile = [&](int buf) {
        *(bf16x8*)&Ks[buf][srow * LDK + scol]        = kr0;
        *(bf16x8*)&Ks[buf][(srow + 32) * LDK + scol] = kr1;
        *(bf16x8*)&Vs[buf][srow * LDK + scol]        = vr0;
        *(bf16x8*)&Vs[buf][(srow + 32) * LDK + scol] = vr1;
    };

    load_tile(kt0);
    store_tile(0);
    __syncthreads();

    for (int kt = kt0; kt < kend; ++kt) {
        const int cur = (kt - kt0) & 1;
        const bool more = (kt + 1 < kend);
        if (more) load_tile(kt + 1);

        // ---- S = (Q*scale*log2e) K^T : K-frags loaded once, used by both sub-strips ----
        f32x4 sacc[2][4];
        #pragma unroll
        for (int t = 0; t < 4; ++t) {
            bf16x8 b0 = *(const bf16x8*)&Ks[cur][(t * 16 + l15) * LDK + quad * 8];
            bf16x8 b1 = *(const bf16x8*)&Ks[cur][(t * 16 + l15) * LDK + 32 + quad * 8];
            #pragma unroll
            for (int sub = 0; sub < 2; ++sub) {
                f32x4 cc = (f32x4){0.f, 0.f, 0.f, 0.f};
                cc = __builtin_amdgcn_mfma_f32_16x16x32_bf16(a[sub][0], b0, cc, 0, 0, 0);
                cc = __builtin_amdgcn_mfma_f32_16x16x32_bf16(a[sub][1], b1, cc, 0, 0, 0);
                sacc[sub][t] = cc;
            }
        }

        // ---- P = 2^S, causal mask in absolute gathered coords ----
        const bool maskTile = causal && (kt >= diag0);
        #pragma unroll
        for (int sub = 0; sub < 2; ++sub) {
            #pragma unroll
            for (int t = 0; t < 4; ++t) {
                const int gcol = (kt << 6) + t * 16 + l15;
                #pragma unroll
                for (int r = 0; r < 4; ++r) {
                    const int grow = qb + wave * 32 + sub * 16 + quad * 4 + r;
                    float p = exp2f(sacc[sub][t][r]);
                    if (maskTile && gcol > grow) p = 0.f;
                    l_r[sub * 4 + r] += p;
                    Ps[wave][(sub * 16 + quad * 4 + r) * LDK + t * 16 + l15] = (__bf16)p;
                }
            }
        }

        // ---- O += P V : V-frags loaded once, used by both sub-strips ----
        bf16x8 p0[2], p1[2];
        #pragma unroll
        for (int sub = 0; sub < 2; ++sub) {
            p0[sub] = *(const bf16x8*)&Ps[wave][(sub * 16 + l15) * LDK + quad * 8];
            p1[sub] = *(const bf16x8*)&Ps[wave][(sub * 16 + l15) * LDK + 32 + quad * 8];
        }
        #pragma unroll
        for (int t = 0; t < 4; ++t) {
            bf16x8 bv0 = *(const bf16x8*)&Vs[cur][(t * 16 + l15) * LDK + quad * 8];
            bf16x8 bv1 = *(const bf16x8*)&Vs[cur][(t * 16 + l15) * LDK + 32 + quad * 8];
            #pragma unroll
            for (int sub = 0; sub < 2; ++sub) {
                o[sub][t] = __builtin_amdgcn_mfma_f32_16x16x32_bf16(p0[sub], bv0, o[sub][t], 0, 0, 0);
                o[sub][t] = __builtin_amdgcn_mfma_f32_16x16x32_bf16(p1[sub], bv1, o[sub][t], 0, 0, 0);
            }
        }

        if (more) store_tile(cur ^ 1);
        __syncthreads();
    }

    // ---- epilogue ----
    #pragma unroll
    for (int off = 1; off < 16; off <<= 1) {
        #pragma unroll
        for (int i = 0; i < 8; ++i)
            l_r[i] += __shfl_xor(l_r[i], off, 64);
    }
    if (nch == 1) {
        #pragma unroll
        for (int sub = 0; sub < 2; ++sub) {
            #pragma unroll
            for (int r = 0; r < 4; ++r) {
                const float inv = 1.0f / l_r[sub * 4 + r];
                const int row = q0 + wave * 32 + sub * 16 + quad * 4 + r;
                #pragma unroll
                for (int t = 0; t < 4; ++t)
                    Out[(size_t)row * HD + h * 64 + t * 16 + l15] = o[sub][t][r] * inv;
            }
        }
    } else {
        #pragma unroll
        for (int sub = 0; sub < 2; ++sub) {
            #pragma unroll
            for (int r = 0; r < 4; ++r) {
                const int row = q0 + wave * 32 + sub * 16 + quad * 4 + r;
                if (l15 == 0) atomicAdd(&l_acc[row * 12 + h], l_r[sub * 4 + r]);
                #pragma unroll
                for (int t = 0; t < 4; ++t)
                    atomicAdd(&Out[(size_t)row * HD + h * 64 + t * 16 + l15], o[sub][t][r]);
            }
        }
    }
}

// ---------------- finalize: divide multi-chunk rows by accumulated l ----------------
__global__ __launch_bounds__(256)
void finalize_kernel(float* __restrict__ Out, const float* __restrict__ l_acc,
                     const int* __restrict__ is_causal_p)
{
    const int causal = (*is_causal_p) != 0;
    const int idx = blockIdx.x * 256 + threadIdx.x;
    const int rh = idx >> 4;
    const int d4 = idx & 15;
    const int h = rh % 12;
    const int row = rh / 12;
    const int group = h >> 2;
    const int sl = 1024 << group;
    const int q0 = (row >> 7) << 7;                  // 128-row tile base
    const int qb = q0 & (sl - 1);
    const int nkt = causal ? ((qb >> 6) + 2) : (sl >> 6);
    if (nkt <= 16) return;                           // single chunk: already normalized
    const float inv = 1.0f / l_acc[rh];
    float4* p = (float4*)Out + (size_t)rh * 16 + d4;
    float4 v = *p;
    v.x *= inv; v.y *= inv; v.z *= inv; v.w *= inv;
    *p = v;
}

extern "C" void kernel_launch(void* const* d_in, const int* in_sizes, int n_in,
                              void* d_out, int out_size, void* d_ws, size_t ws_size,
                              hipStream_t stream) {
    (void)in_sizes; (void)n_in; (void)out_size; (void)ws_size;
    const float* Q = (const float*)d_in[0];
    const float* K = (const float*)d_in[1];
    const float* V = (const float*)d_in[2];
    const int* isc = (const int*)d_in[3];
    float* Out = (float*)d_out;
    ushort_t* Kg   = (ushort_t*)((char*)d_ws + KG_OFF);
    ushort_t* VgT  = (ushort_t*)((char*)d_ws + VGT_OFF);
    float*    lacc = (float*)((char*)d_ws + LACC_OFF);

    hipMemsetAsync(Out, 0, (size_t)4096 * 12 * 64 * 4, stream);
    hipMemsetAsync(lacc, 0, (size_t)4096 * 12 * 4, stream);
    preconvert_kernel<<<1536, 256, 0, stream>>>(K, V, Kg, VgT);
    dilated_attn_kernel<<<1536, 256, 0, stream>>>(Q, Kg, VgT, isc, Out, lacc);
    finalize_kernel<<<3072, 256, 0, stream>>>(Out, lacc, isc);
}